// Round 2
// baseline (406.102 us; speedup 1.0000x reference)
//
#include <hip/hip_runtime.h>

// conv2d NCHW fp32: X[32,64,112,112] * W[128,64,3,3], pad=1 -> out[32,128,112,112].
//
// v2b: v2 with the staging over-read clamped (no reads past Xt end).
// Structure: the old kernel spent its time on in-kernel f32->bf16 shfl-transpose
// staging (VALUBusy 47% vs MfmaUtil 17%), re-done 2x per input element across
// overlapping blocks. Now a memory-bound prep pass writes Xt[b][hp][wp][c]
// bf16 with zero halo (hp=h+1, wp=w+1); the conv kernel stages LDS with
// global_load_lds (zero VALU), applying the XOR chunk swizzle to the per-lane
// GLOBAL source address (LDS dest must stay linear, m104/m173). Waves own 64
// filters -> half the LDS b128 read traffic vs 32. Falls back to the old
// kernel if ws_size can't hold Xt (51 MB).

typedef __attribute__((ext_vector_type(8))) __bf16 bf16x8;
typedef __attribute__((ext_vector_type(4))) float f32x4;
typedef __attribute__((ext_vector_type(4))) unsigned int u32x4;

#define XROW 7296   // shorts per Xt (b,hp) row: 114 wp * 64 c
#define WPROW 120   // padded wp entries per LDS row (15 segs of 8 chunks)

__device__ __forceinline__ unsigned short f2bf(float f) {
    unsigned u = __builtin_bit_cast(unsigned, f);
    u += 0x7FFF + ((u >> 16) & 1);  // round-to-nearest-even
    return (unsigned short)(u >> 16);
}

__device__ __forceinline__ void gload_lds16(const unsigned short* g, unsigned short* l) {
    __builtin_amdgcn_global_load_lds(
        (const __attribute__((address_space(1))) unsigned int*)g,
        (__attribute__((address_space(3))) unsigned int*)l, 16, 0, 0);
}

// ---- prep: W[f][c][kh][kw] fp32 -> wsA[off][f][c] bf16 (off = kh*3+kw) ----
__global__ void prep_weights(const float* __restrict__ flt,
                             unsigned short* __restrict__ wsA) {
    int idx = blockIdx.x * 256 + threadIdx.x;
    if (idx >= 9 * 128 * 64) return;
    int off = idx >> 13;
    int f   = (idx >> 6) & 127;
    int c   = idx & 63;
    wsA[idx] = f2bf(flt[(f * 64 + c) * 9 + off]);
}

// ---- prep: X[b][c][h][w] f32 -> Xt[b][hp][wp][c] bf16, zero-padded halo ----
// One block per (b,h). Transpose 64c x 112w via the 8x8 shfl butterfly into a
// chunk-swizzled LDS tile, then write the padded row coalesced (with wp=0/113
// zero columns folded into the copy). Rows hp=0/113 zeroed by edge blocks.
__global__ __launch_bounds__(512, 4)
void prep_input(const float* __restrict__ x, unsigned short* __restrict__ xt) {
    __shared__ __align__(16) unsigned short T[112 * 64];
    const int tid  = threadIdx.x;
    const int b    = blockIdx.x / 112;
    const int h    = blockIdx.x - b * 112;
    const int li   = tid & 7;
    const int unit = tid >> 3;

    for (int it = 0; it < 2; ++it) {
        int u = it * 64 + unit;            // [0,128), valid < 112
        if (u < 112) {
            int wo = u >> 3, cq = u & 7;
            int c  = cq * 8 + li;
            const float* src = x + (((size_t)b * 64 + c) * 112 + h) * 112 + wo * 8;
            f32x4 f0 = *(const f32x4*)src;
            f32x4 f1 = *(const f32x4*)(src + 4);
            float r[8] = {f0.x, f0.y, f0.z, f0.w, f1.x, f1.y, f1.z, f1.w};
#pragma unroll
            for (int d = 1; d < 8; d <<= 1) {
#pragma unroll
                for (int jA = 0; jA < 8; ++jA) {
                    if (jA & d) continue;
                    int jB = jA | d;
                    float give = (li & d) ? r[jA] : r[jB];
                    float got  = __shfl_xor(give, d, 64);
                    if (li & d) r[jA] = got; else r[jB] = got;
                }
            }
            unsigned pk[4];
#pragma unroll
            for (int j = 0; j < 4; ++j)
                pk[j] = (unsigned)f2bf(r[2 * j]) | ((unsigned)f2bf(r[2 * j + 1]) << 16);
            int w = wo * 8 + li;           // lane holds c=cq*8+0..7 for this w
            *(u32x4*)&T[w * 64 + (cq ^ (w & 7)) * 8] = u32x4{pk[0], pk[1], pk[2], pk[3]};
        }
    }
    __syncthreads();

    unsigned short* dst = xt + ((size_t)b * 114 + (h + 1)) * XROW;
    for (int ch = tid; ch < 912; ch += 512) {   // 114 wp * 8 cq chunks of 16B
        int wp = ch >> 3, cq = ch & 7;
        u32x4 v = {0, 0, 0, 0};
        if (wp >= 1 && wp <= 112) {
            int w = wp - 1;
            v = *(const u32x4*)&T[w * 64 + (cq ^ (w & 7)) * 8];
        }
        *(u32x4*)&dst[(size_t)ch * 8] = v;
    }
    if (h == 0 || h == 111) {
        unsigned short* zr = xt + ((size_t)b * 114 + (h == 0 ? 0 : 113)) * XROW;
        for (int ch = tid; ch < 912; ch += 512)
            *(u32x4*)&zr[(size_t)ch * 8] = u32x4{0, 0, 0, 0};
    }
}

// ---- fast conv: per-wave K-loop over 64 filters x NTW w-tiles of one row ----
template <int TW0, int NTW>
__device__ __forceinline__ void wave_kloop(const unsigned short* Bs,
                                           const unsigned short* wA,
                                           float* obase, int rr, int l16, int q) {
    f32x4 acc[4][NTW];
#pragma unroll
    for (int mt = 0; mt < 4; ++mt)
#pragma unroll
        for (int t = 0; t < NTW; ++t) acc[mt][t] = {0.f, 0.f, 0.f, 0.f};

#pragma unroll
    for (int off = 0; off < 9; ++off) {
        const int kh = off / 3;            // compile-time (unrolled)
        const int kw = off - kh * 3;
        const int rp = rr + kh;
#pragma unroll
        for (int cs = 0; cs < 2; ++cs) {
            bf16x8 a0 = *(const bf16x8*)(wA + off * 8192 + cs * 32);
            bf16x8 a1 = *(const bf16x8*)(wA + off * 8192 + 1024 + cs * 32);
            bf16x8 a2 = *(const bf16x8*)(wA + off * 8192 + 2048 + cs * 32);
            bf16x8 a3 = *(const bf16x8*)(wA + off * 8192 + 3072 + cs * 32);
            const int cq = cs * 4 + q;
#pragma unroll
            for (int t = 0; t < NTW; ++t) {
                int wp = (TW0 + t) * 16 + l16 + kw;
                int chunk = cq ^ (wp & 7);
                bf16x8 bv = *(const bf16x8*)&Bs[(rp * WPROW + wp) * 64 + chunk * 8];
                acc[0][t] = __builtin_amdgcn_mfma_f32_16x16x32_bf16(a0, bv, acc[0][t], 0, 0, 0);
                acc[1][t] = __builtin_amdgcn_mfma_f32_16x16x32_bf16(a1, bv, acc[1][t], 0, 0, 0);
                acc[2][t] = __builtin_amdgcn_mfma_f32_16x16x32_bf16(a2, bv, acc[2][t], 0, 0, 0);
                acc[3][t] = __builtin_amdgcn_mfma_f32_16x16x32_bf16(a3, bv, acc[3][t], 0, 0, 0);
            }
        }
    }
#pragma unroll
    for (int mt = 0; mt < 4; ++mt)
#pragma unroll
        for (int t = 0; t < NTW; ++t) {
            float* o = obase + (size_t)(mt * 16) * 12544 + (TW0 + t) * 16 + l16;
#pragma unroll
            for (int r2 = 0; r2 < 4; ++r2)
                o[(size_t)r2 * 12544] = acc[mt][t][r2];
        }
}

__global__ __launch_bounds__(512, 4)
void conv_fast(const unsigned short* __restrict__ xt,
               const unsigned short* __restrict__ wsA,
               float* __restrict__ out) {
    // Bs: 4 input rows x 120 wp x 64 c shorts, chunk-XOR-swizzled. 61440 B.
    __shared__ __align__(16) unsigned short Bs[4 * WPROW * 64];

    const int tid = threadIdx.x;
    const int id  = blockIdx.x;            // 1792 = 32 b x 56 h-pairs
    const int xcd = id & 7;
    const int s   = id >> 3;
    const int b   = s / 7;
    const int hpl = s - b * 7;
    const int h0  = (xcd * 7 + hpl) * 2;   // contiguous h-strip per XCD

    const int lane = tid & 63;
    const int wid  = tid >> 6;

    // ---- stage Xt rows hp0..hp0+3 (padded coords): 60 wave-segs of 1 KiB ----
    // LDS dest is wave-uniform base + lane*16 (linear); the XOR chunk swizzle
    // is applied to the per-lane GLOBAL source. Lanes that would read wp>113
    // (LDS slack slots, never consumed) are clamped to wp=113 -> no OOB reads.
    {
        const unsigned short* xbase = xt + ((size_t)b * 114 + h0) * XROW;
        const int l3 = lane >> 3, j = lane & 7;
        for (int i = wid; i < 60; i += 8) {
            int rp  = i / 15;
            int seg = i - rp * 15;
            int wp  = seg * 8 + l3;                 // up to 119
            int wps = wp <= 113 ? wp : 113;         // clamp: no read past Xt
            const unsigned short* src =
                xbase + (size_t)rp * XROW + wps * 64 + ((j ^ (wps & 7)) * 8);
            gload_lds16(src, &Bs[(rp * WPROW + seg * 8) * 64]);
        }
    }
    __syncthreads();   // the only barrier (drains vmcnt for global_load_lds)

    const int l16 = lane & 15;
    const int q   = lane >> 4;
    const int fg  = wid & 1;               // 64-filter group
    const int rr  = (wid >> 1) & 1;        // output row h0 + rr
    const int ws  = wid >> 2;              // w-split: tw 0..3 / 4..6
    const int h   = h0 + rr;

    const unsigned short* wA = wsA + (fg * 64 + l16) * 64 + q * 8;
    float* obase = out + (((size_t)b * 128 + fg * 64 + q * 4) * 112 + h) * 112;

    if (ws == 0) wave_kloop<0, 4>(Bs, wA, obase, rr, l16, q);
    else         wave_kloop<4, 3>(Bs, wA, obase, rr, l16, q);
}

// ======================= fallback (old kernel, unchanged) ====================
#define ROWS_PER_KH 124
#define ROW_SHORTS 64

__global__ __launch_bounds__(512, 4)
void conv_mfma(const float* __restrict__ x,
               const unsigned short* __restrict__ wsA,
               float* __restrict__ out) {
    __shared__ __align__(16) unsigned short Bso[4 * ROWS_PER_KH * ROW_SHORTS];

    const int tid = threadIdx.x;
    const int id  = blockIdx.x;
    const int xcd = id & 7;
    const int s   = id >> 3;
    const int b   = s / 7;
    const int hpl = s - b * 7;
    const int hp  = xcd * 7 + hpl;
    const int h0  = hp * 2;

    if (tid < 32) {
        int kh = tid >> 3, cq = tid & 7;
        int R = kh * ROWS_PER_KH;
        int chunk = cq ^ (R & 7);
        *(u32x4*)&Bso[R * ROW_SHORTS + chunk * 8] = u32x4{0, 0, 0, 0};
    }

    const int li   = tid & 7;
    const int unit = tid >> 3;
    for (int it = 0; it < 8; ++it) {
        int u = it * 64 + unit;
        if (u < 480) {
            int wo = u >> 5;
            int rc = u & 31;
            int rp = rc >> 3;
            int cq = rc & 7;
            int hr = h0 + rp - 1;
            int c  = cq * 8 + li;
            f32x4 f0 = {0.f, 0.f, 0.f, 0.f}, f1 = {0.f, 0.f, 0.f, 0.f};
            if ((unsigned)hr < 112u && wo < 14) {
                const float* src = x + (((size_t)b * 64 + c) * 112 + hr) * 112 + wo * 8;
                f0 = *(const f32x4*)src;
                f1 = *(const f32x4*)(src + 4);
            }
            float r[8] = {f0.x, f0.y, f0.z, f0.w, f1.x, f1.y, f1.z, f1.w};
#pragma unroll
            for (int d = 1; d < 8; d <<= 1) {
#pragma unroll
                for (int jA = 0; jA < 8; ++jA) {
                    if (jA & d) continue;
                    int jB = jA | d;
                    float give = (li & d) ? r[jA] : r[jB];
                    float got  = __shfl_xor(give, d, 64);
                    if (li & d) r[jA] = got; else r[jB] = got;
                }
            }
            int R = rp * ROWS_PER_KH + wo * 8 + li + 1;
            int chunk = cq ^ (R & 7);
            unsigned pk[4];
#pragma unroll
            for (int j = 0; j < 4; ++j)
                pk[j] = (unsigned)f2bf(r[2 * j]) | ((unsigned)f2bf(r[2 * j + 1]) << 16);
            *(u32x4*)&Bso[R * ROW_SHORTS + chunk * 8] = u32x4{pk[0], pk[1], pk[2], pk[3]};
        }
    }
    __syncthreads();

    const int lane = tid & 63;
    const int wid  = tid >> 6;
    const int fg   = wid & 3;
    const int rr   = wid >> 2;
    const int q    = lane >> 4;
    const int l16  = lane & 15;
    const int h    = h0 + rr;

    f32x4 acc[2][7];
#pragma unroll
    for (int mt = 0; mt < 2; ++mt)
#pragma unroll
        for (int tw = 0; tw < 7; ++tw)
            acc[mt][tw] = {0.f, 0.f, 0.f, 0.f};

    const unsigned short* wA = wsA + (fg * 32 + l16) * 64 + q * 8;

#pragma unroll
    for (int off = 0; off < 9; ++off) {
        const int kh = off / 3;
        const int kw = off - kh * 3;
        const int Rbase = (rr + kh) * ROWS_PER_KH + kw;
#pragma unroll
        for (int cs = 0; cs < 2; ++cs) {
            bf16x8 a0 = *(const bf16x8*)(wA + off * 8192 + cs * 32);
            bf16x8 a1 = *(const bf16x8*)(wA + off * 8192 + 1024 + cs * 32);
            const int cq = cs * 4 + q;
#pragma unroll
            for (int tw = 0; tw < 7; ++tw) {
                int R = Rbase + tw * 16 + l16;
                int chunk = cq ^ (R & 7);
                bf16x8 bv = *(const bf16x8*)&Bso[R * ROW_SHORTS + chunk * 8];
                acc[0][tw] = __builtin_amdgcn_mfma_f32_16x16x32_bf16(a0, bv, acc[0][tw], 0, 0, 0);
                acc[1][tw] = __builtin_amdgcn_mfma_f32_16x16x32_bf16(a1, bv, acc[1][tw], 0, 0, 0);
            }
        }
    }

#pragma unroll
    for (int mt = 0; mt < 2; ++mt) {
#pragma unroll
        for (int tw = 0; tw < 7; ++tw) {
            int f = fg * 32 + mt * 16 + q * 4;
            int w = tw * 16 + l16;
            float* o = out + (((size_t)b * 128 + f) * 112 + h) * 112 + w;
#pragma unroll
            for (int r2 = 0; r2 < 4; ++r2)
                o[(size_t)r2 * 12544] = acc[mt][tw][r2];
        }
    }
}

extern "C" void kernel_launch(void* const* d_in, const int* in_sizes, int n_in,
                              void* d_out, int out_size, void* d_ws, size_t ws_size,
                              hipStream_t stream) {
    const float* x   = (const float*)d_in[0];   // dataset [32,64,112,112]
    const float* flt = (const float*)d_in[1];   // filters [128,64,3,3]
    float* out = (float*)d_out;
    unsigned short* wsA = (unsigned short*)d_ws;  // 147456 B weights

    hipLaunchKernelGGL(prep_weights, dim3(288), dim3(256), 0, stream, flt, wsA);

    const size_t XT_BYTES = (size_t)32 * 114 * 114 * 64 * 2;   // 53,231,616
    const size_t need = 147456 + XT_BYTES;                     // no slack needed
    if (ws_size >= need) {
        unsigned short* xxt = wsA + 147456 / 2;
        hipLaunchKernelGGL(prep_input, dim3(3584), dim3(512), 0, stream, x, xxt);
        hipLaunchKernelGGL(conv_fast, dim3(1792), dim3(512), 0, stream, xxt, wsA, out);
    } else {
        hipLaunchKernelGGL(conv_mfma, dim3(1792), dim3(512), 0, stream, x, wsA, out);
    }
}

// Round 3
// 344.776 us; speedup vs baseline: 1.1779x; 1.1779x over previous
//
#include <hip/hip_runtime.h>

// conv2d NCHW fp32: X[32,64,112,112] * W[128,64,3,3], pad=1 -> out[32,128,112,112].
//
// v3: v2b showed VALUBusy 47->10% with dur UNCHANGED (147us) -> latency-bound,
// not VALU-bound. Diagnosis: K-loop weight loads from global (72KB/wave) miss
// the 32KB L1 ~100% (144KB working set) and are served by L3 (~700cyc) with a
// saturated per-CU miss queue; ~80 serialized loads/wave * ~1200cyc = the
// 100k-cycle wave wall. Fix: weights staged in LDS (72KB, one 64-filter group
// per block) + 4 output rows (6 input rows, 85.5KB) => K-loop touches ONLY
// LDS. 1 block/CU, 512 thr, VGPR cap 256 so the compiler can pipeline freely.

typedef __attribute__((ext_vector_type(8))) __bf16 bf16x8;
typedef __attribute__((ext_vector_type(4))) float f32x4;
typedef __attribute__((ext_vector_type(4))) unsigned int u32x4;

#define XROW 7296   // shorts per Xt (b,hp) row: 114 wp * 64 c
#define WPROW 114   // LDS wp rows per staged input row (conv_lds)

__device__ __forceinline__ unsigned short f2bf(float f) {
    unsigned u = __builtin_bit_cast(unsigned, f);
    u += 0x7FFF + ((u >> 16) & 1);  // round-to-nearest-even
    return (unsigned short)(u >> 16);
}

__device__ __forceinline__ void gload_lds16(const unsigned short* g, unsigned short* l) {
    __builtin_amdgcn_global_load_lds(
        (const __attribute__((address_space(1))) unsigned int*)g,
        (__attribute__((address_space(3))) unsigned int*)l, 16, 0, 0);
}
__device__ __forceinline__ void gload_lds4(const unsigned short* g, unsigned short* l) {
    __builtin_amdgcn_global_load_lds(
        (const __attribute__((address_space(1))) unsigned int*)g,
        (__attribute__((address_space(3))) unsigned int*)l, 4, 0, 0);
}

// ---- prep: W[f][c][kh][kw] fp32 -> wsA[off][f][c] (plain, for fallback) and
// wsS[off][f][c-chunk-XOR-swizzled] (for LDS staging; slot s of row f holds
// c-octet s^(f&7), so a linear LDS copy yields conflict-free b128 A-reads) ----
__global__ void prep_weights(const float* __restrict__ flt,
                             unsigned short* __restrict__ wsA,
                             unsigned short* __restrict__ wsS) {
    int idx = blockIdx.x * 256 + threadIdx.x;
    if (idx >= 9 * 128 * 64) return;
    int off = idx >> 13;
    int f   = (idx >> 6) & 127;
    int c   = idx & 63;
    unsigned short v = f2bf(flt[(f * 64 + c) * 9 + off]);
    wsA[idx] = v;
    int cq = c >> 3, cl = c & 7;
    wsS[(off * 128 + f) * 64 + ((cq ^ (f & 7)) * 8 + cl)] = v;
}

// ---- prep: X[b][c][h][w] f32 -> Xt[b][hp][wp][c] bf16, zero-padded halo ----
__global__ __launch_bounds__(512, 4)
void prep_input(const float* __restrict__ x, unsigned short* __restrict__ xt) {
    __shared__ __align__(16) unsigned short T[112 * 64];
    const int tid  = threadIdx.x;
    const int b    = blockIdx.x / 112;
    const int h    = blockIdx.x - b * 112;
    const int li   = tid & 7;
    const int unit = tid >> 3;

    for (int it = 0; it < 2; ++it) {
        int u = it * 64 + unit;            // [0,128), valid < 112
        if (u < 112) {
            int wo = u >> 3, cq = u & 7;
            int c  = cq * 8 + li;
            const float* src = x + (((size_t)b * 64 + c) * 112 + h) * 112 + wo * 8;
            f32x4 f0 = *(const f32x4*)src;
            f32x4 f1 = *(const f32x4*)(src + 4);
            float r[8] = {f0.x, f0.y, f0.z, f0.w, f1.x, f1.y, f1.z, f1.w};
#pragma unroll
            for (int d = 1; d < 8; d <<= 1) {
#pragma unroll
                for (int jA = 0; jA < 8; ++jA) {
                    if (jA & d) continue;
                    int jB = jA | d;
                    float give = (li & d) ? r[jA] : r[jB];
                    float got  = __shfl_xor(give, d, 64);
                    if (li & d) r[jA] = got; else r[jB] = got;
                }
            }
            unsigned pk[4];
#pragma unroll
            for (int j = 0; j < 4; ++j)
                pk[j] = (unsigned)f2bf(r[2 * j]) | ((unsigned)f2bf(r[2 * j + 1]) << 16);
            int w = wo * 8 + li;
            *(u32x4*)&T[w * 64 + (cq ^ (w & 7)) * 8] = u32x4{pk[0], pk[1], pk[2], pk[3]};
        }
    }
    __syncthreads();

    unsigned short* dst = xt + ((size_t)b * 114 + (h + 1)) * XROW;
    for (int ch = tid; ch < 912; ch += 512) {   // 114 wp * 8 cq chunks of 16B
        int wp = ch >> 3, cq = ch & 7;
        u32x4 v = {0, 0, 0, 0};
        if (wp >= 1 && wp <= 112) {
            int w = wp - 1;
            v = *(const u32x4*)&T[w * 64 + (cq ^ (w & 7)) * 8];
        }
        *(u32x4*)&dst[(size_t)ch * 8] = v;
    }
    if (h == 0 || h == 111) {
        unsigned short* zr = xt + ((size_t)b * 114 + (h == 0 ? 0 : 113)) * XROW;
        for (int ch = tid; ch < 912; ch += 512)
            *(u32x4*)&zr[(size_t)ch * 8] = u32x4{0, 0, 0, 0};
    }
}

// ---- all-LDS K-loop: 64 filters x NTW w-tiles x 1 output row per wave ----
template <int TW0, int NTW>
__device__ __forceinline__ void kloop_lds(const unsigned short* Ws,
                                          const unsigned short* Bs,
                                          float* obase, int rr, int l16, int q) {
    f32x4 acc[4][NTW];
#pragma unroll
    for (int mt = 0; mt < 4; ++mt)
#pragma unroll
        for (int t = 0; t < NTW; ++t) acc[mt][t] = {0.f, 0.f, 0.f, 0.f};

    const int e = l16 & 7;
#pragma unroll
    for (int off = 0; off < 9; ++off) {
        const int kh = off / 3;            // compile-time (unrolled)
        const int kw = off - kh * 3;
        const int rp = rr + kh;
#pragma unroll
        for (int cs = 0; cs < 2; ++cs) {
            const int cq = cs * 4 + q;
            const int ca = cq ^ e;         // A chunk (conflict-free, same family as B)
            bf16x8 a0 = *(const bf16x8*)&Ws[(off * 64 +      l16) * 64 + ca * 8];
            bf16x8 a1 = *(const bf16x8*)&Ws[(off * 64 + 16 + l16) * 64 + ca * 8];
            bf16x8 a2 = *(const bf16x8*)&Ws[(off * 64 + 32 + l16) * 64 + ca * 8];
            bf16x8 a3 = *(const bf16x8*)&Ws[(off * 64 + 48 + l16) * 64 + ca * 8];
#pragma unroll
            for (int t = 0; t < NTW; ++t) {
                int wp = (TW0 + t) * 16 + l16 + kw;
                int cb = cq ^ (wp & 7);
                bf16x8 bv = *(const bf16x8*)&Bs[(rp * WPROW + wp) * 64 + cb * 8];
                acc[0][t] = __builtin_amdgcn_mfma_f32_16x16x32_bf16(a0, bv, acc[0][t], 0, 0, 0);
                acc[1][t] = __builtin_amdgcn_mfma_f32_16x16x32_bf16(a1, bv, acc[1][t], 0, 0, 0);
                acc[2][t] = __builtin_amdgcn_mfma_f32_16x16x32_bf16(a2, bv, acc[2][t], 0, 0, 0);
                acc[3][t] = __builtin_amdgcn_mfma_f32_16x16x32_bf16(a3, bv, acc[3][t], 0, 0, 0);
            }
        }
    }
#pragma unroll
    for (int mt = 0; mt < 4; ++mt)
#pragma unroll
        for (int t = 0; t < NTW; ++t) {
            float* o = obase + (size_t)(mt * 16) * 12544 + (TW0 + t) * 16 + l16;
#pragma unroll
            for (int r2 = 0; r2 < 4; ++r2)
                o[(size_t)r2 * 12544] = acc[mt][t][r2];
        }
}

__global__ __launch_bounds__(512, 2)
void conv_lds(const unsigned short* __restrict__ xt,
              const unsigned short* __restrict__ wsS,
              float* __restrict__ out) {
    __shared__ __align__(16) unsigned short Ws[9 * 64 * 64];      // 73728 B
    __shared__ __align__(16) unsigned short Bs[6 * WPROW * 64];   // 87552 B

    const int tid = threadIdx.x;
    const int id  = blockIdx.x;            // 1792 = 32 b x 28 h-quads x 2 fg
    const int xcd = id & 7;
    const int s   = id >> 3;               // [0,224)
    const int b   = s / 7;
    const int u   = s - b * 7;
    const int ix  = xcd * 7 + u;           // [0,56) — contiguous strip per XCD
    const int fg  = ix & 1;                // 64-filter group
    const int quad = ix >> 1;              // [0,28): output rows quad*4..+3

    const int lane = tid & 63;
    const int wid  = tid >> 6;

    // ---- stage: 72 weight segs (linear copy of pre-swizzled wsS half) +
    //      84 input segs (swizzle on global source) + 6 width-4 tails ----
    const unsigned short* xrow = xt + ((size_t)b * 114 + quad * 4) * XROW;
    {
        const int l3 = lane >> 3, j = lane & 7;
        for (int i = wid; i < 156; i += 8) {
            if (i < 72) {
                int off = i >> 3, k = i & 7;
                gload_lds16(wsS + off * 8192 + fg * 4096 + k * 512 + lane * 8,
                            &Ws[off * 4096 + k * 512]);
            } else {
                int i2 = i - 72;
                int rp = i2 / 14, seg = i2 - rp * 14;
                int wp = seg * 8 + l3;                 // <= 111
                gload_lds16(xrow + (size_t)rp * XROW + wp * 64 + ((j ^ (wp & 7)) * 8),
                            &Bs[(rp * WPROW + seg * 8) * 64]);
            }
        }
        if (wid < 6) {   // tail wp=112,113 per input row: 256B width-4 copy
            int rp = wid;
            int wp = 112 + (lane >> 5);
            int cq = (lane & 31) >> 2;
            gload_lds4(xrow + (size_t)rp * XROW + wp * 64 + (cq ^ (wp & 7)) * 8 + (lane & 3) * 2,
                       &Bs[(rp * WPROW + 112) * 64]);
        }
    }
    __syncthreads();   // the only barrier (drains vmcnt for global_load_lds)

    const int l16 = lane & 15;
    const int q   = lane >> 4;
    const int rr  = wid & 3;               // output row quad*4 + rr
    const int ws  = wid >> 2;              // w-split (balanced across SIMDs)
    const int h   = quad * 4 + rr;

    float* obase = out + (((size_t)b * 128 + fg * 64 + q * 4) * 112 + h) * 112;

    if (ws == 0) kloop_lds<0, 4>(Ws, Bs, obase, rr, l16, q);
    else         kloop_lds<4, 3>(Ws, Bs, obase, rr, l16, q);
}

// ======================= fallback (old kernel, unchanged) ====================
#define ROWS_PER_KH 124
#define ROW_SHORTS 64

__global__ __launch_bounds__(512, 4)
void conv_mfma(const float* __restrict__ x,
               const unsigned short* __restrict__ wsA,
               float* __restrict__ out) {
    __shared__ __align__(16) unsigned short Bso[4 * ROWS_PER_KH * ROW_SHORTS];

    const int tid = threadIdx.x;
    const int id  = blockIdx.x;
    const int xcd = id & 7;
    const int s   = id >> 3;
    const int b   = s / 7;
    const int hpl = s - b * 7;
    const int hp  = xcd * 7 + hpl;
    const int h0  = hp * 2;

    if (tid < 32) {
        int kh = tid >> 3, cq = tid & 7;
        int R = kh * ROWS_PER_KH;
        int chunk = cq ^ (R & 7);
        *(u32x4*)&Bso[R * ROW_SHORTS + chunk * 8] = u32x4{0, 0, 0, 0};
    }

    const int li   = tid & 7;
    const int unit = tid >> 3;
    for (int it = 0; it < 8; ++it) {
        int u = it * 64 + unit;
        if (u < 480) {
            int wo = u >> 5;
            int rc = u & 31;
            int rp = rc >> 3;
            int cq = rc & 7;
            int hr = h0 + rp - 1;
            int c  = cq * 8 + li;
            f32x4 f0 = {0.f, 0.f, 0.f, 0.f}, f1 = {0.f, 0.f, 0.f, 0.f};
            if ((unsigned)hr < 112u && wo < 14) {
                const float* src = x + (((size_t)b * 64 + c) * 112 + hr) * 112 + wo * 8;
                f0 = *(const f32x4*)src;
                f1 = *(const f32x4*)(src + 4);
            }
            float r[8] = {f0.x, f0.y, f0.z, f0.w, f1.x, f1.y, f1.z, f1.w};
#pragma unroll
            for (int d = 1; d < 8; d <<= 1) {
#pragma unroll
                for (int jA = 0; jA < 8; ++jA) {
                    if (jA & d) continue;
                    int jB = jA | d;
                    float give = (li & d) ? r[jA] : r[jB];
                    float got  = __shfl_xor(give, d, 64);
                    if (li & d) r[jA] = got; else r[jB] = got;
                }
            }
            int R = rp * ROWS_PER_KH + wo * 8 + li + 1;
            int chunk = cq ^ (R & 7);
            unsigned pk[4];
#pragma unroll
            for (int j = 0; j < 4; ++j)
                pk[j] = (unsigned)f2bf(r[2 * j]) | ((unsigned)f2bf(r[2 * j + 1]) << 16);
            *(u32x4*)&Bso[R * ROW_SHORTS + chunk * 8] = u32x4{pk[0], pk[1], pk[2], pk[3]};
        }
    }
    __syncthreads();

    const int lane = tid & 63;
    const int wid  = tid >> 6;
    const int fg   = wid & 3;
    const int rr   = wid >> 2;
    const int q    = lane >> 4;
    const int l16  = lane & 15;
    const int h    = h0 + rr;

    f32x4 acc[2][7];
#pragma unroll
    for (int mt = 0; mt < 2; ++mt)
#pragma unroll
        for (int tw = 0; tw < 7; ++tw)
            acc[mt][tw] = {0.f, 0.f, 0.f, 0.f};

    const unsigned short* wA = wsA + (fg * 32 + l16) * 64 + q * 8;

#pragma unroll
    for (int off = 0; off < 9; ++off) {
        const int kh = off / 3;
        const int kw = off - kh * 3;
        const int Rbase = (rr + kh) * ROWS_PER_KH + kw;
#pragma unroll
        for (int cs = 0; cs < 2; ++cs) {
            bf16x8 a0 = *(const bf16x8*)(wA + off * 8192 + cs * 32);
            bf16x8 a1 = *(const bf16x8*)(wA + off * 8192 + 1024 + cs * 32);
            const int cq = cs * 4 + q;
#pragma unroll
            for (int tw = 0; tw < 7; ++tw) {
                int R = Rbase + tw * 16 + l16;
                int chunk = cq ^ (R & 7);
                bf16x8 bv = *(const bf16x8*)&Bso[R * ROW_SHORTS + chunk * 8];
                acc[0][tw] = __builtin_amdgcn_mfma_f32_16x16x32_bf16(a0, bv, acc[0][tw], 0, 0, 0);
                acc[1][tw] = __builtin_amdgcn_mfma_f32_16x16x32_bf16(a1, bv, acc[1][tw], 0, 0, 0);
            }
        }
    }

#pragma unroll
    for (int mt = 0; mt < 2; ++mt) {
#pragma unroll
        for (int tw = 0; tw < 7; ++tw) {
            int f = fg * 32 + mt * 16 + q * 4;
            int w = tw * 16 + l16;
            float* o = out + (((size_t)b * 128 + f) * 112 + h) * 112 + w;
#pragma unroll
            for (int r2 = 0; r2 < 4; ++r2)
                o[(size_t)r2 * 12544] = acc[mt][tw][r2];
        }
    }
}

extern "C" void kernel_launch(void* const* d_in, const int* in_sizes, int n_in,
                              void* d_out, int out_size, void* d_ws, size_t ws_size,
                              hipStream_t stream) {
    const float* x   = (const float*)d_in[0];   // dataset [32,64,112,112]
    const float* flt = (const float*)d_in[1];   // filters [128,64,3,3]
    float* out = (float*)d_out;
    unsigned short* wsA = (unsigned short*)d_ws;       // plain weights (fallback)
    unsigned short* wsS = wsA + 73728;                 // swizzled weights (conv_lds)
    unsigned short* xxt = wsA + 147456;                // Xt [32][114][114][64]

    hipLaunchKernelGGL(prep_weights, dim3(288), dim3(256), 0, stream, flt, wsA, wsS);

    const size_t XT_SHORTS = (size_t)32 * 114 * 114 * 64;      // 26,615,808
    const size_t need = (147456 + XT_SHORTS) * 2;              // 53,526,528 B
    if (ws_size >= need) {
        hipLaunchKernelGGL(prep_input, dim3(3584), dim3(512), 0, stream, x, xxt);
        hipLaunchKernelGGL(conv_lds, dim3(1792), dim3(512), 0, stream, xxt, wsS, out);
    } else {
        hipLaunchKernelGGL(conv_mfma, dim3(1792), dim3(512), 0, stream, x, wsA, out);
    }
}